// Round 2
// baseline (269.796 us; speedup 1.0000x reference)
//
#include <hip/hip_runtime.h>
#include <hip/hip_bf16.h>

#define S_NODES 8192
#define P_PATHS 16
#define K_EP    16
#define D_DIM   128
#define H_DIM   64

typedef __bf16 bf16x8_t __attribute__((ext_vector_type(8)));
typedef float  f32x4_t  __attribute__((ext_vector_type(4)));

// LDS strides (words/elements per row), chosen so every hot access is <=2-way bank aliased (free):
#define AGGF_STRIDE  132   // floats; float4 writes land dense -> conflict-free
#define AGGBF_STRIDE 136   // bf16; 272B rows, 16B-aligned for b128 A-frag reads
#define W1T_STRIDE   130   // bf16; lane-stride 65 words == 1 mod 32 -> staging writes conflict-free

__global__ __launch_bounds__(256)
void PathGuidedAggregator_kernel(const float* __restrict__ ent,
                                 const float* __restrict__ W1,
                                 const float* __restrict__ b1,
                                 const float* __restrict__ W2,
                                 const float* __restrict__ b2,
                                 const int*   __restrict__ sids,
                                 const int*   __restrict__ eids,
                                 const void*  __restrict__ emask,
                                 float*       __restrict__ out)
{
    __shared__ float  aggf [P_PATHS][AGGF_STRIDE];   // fp32 agg (for w*agg epilogue)
    __shared__ __bf16 aggbf[P_PATHS][AGGBF_STRIDE];  // bf16 agg (MFMA A operand)
    __shared__ __bf16 w1t  [H_DIM][W1T_STRIDE];      // W1 transposed [j][d] (MFMA B operand)
    __shared__ float  b1s[H_DIM];
    __shared__ float  w2s[H_DIM];
    __shared__ int    cnts[P_PATHS];

    const int s    = blockIdx.x;
    const int tid  = threadIdx.x;
    const int wave = tid >> 6;
    const int lane = tid & 63;

    // ---- stage W1 (transposed -> bf16) into LDS; stride 130 makes these writes 2-way (free) ----
    #pragma unroll
    for (int it = 0; it < 32; ++it) {
        int idx = tid + it * 256;            // coalesced read of W1[d][j]
        int d = idx >> 6, j = idx & 63;
        w1t[j][d] = (__bf16)W1[idx];
    }
    if (tid < H_DIM) { b1s[tid] = b1[tid]; w2s[tid] = W2[tid]; }

    // ---- runtime detection of bool-mask storage: int32 / uint8 / float32 ----
    const unsigned int* mw = (const unsigned int*)emask;
    unsigned int probe = mw[lane];
    const bool floatMask = (__ballot(probe == 0x3F800000u) != 0ULL);
    const bool byteMask  = !floatMask && (__ballot(probe > 1u) != 0ULL);

    // ---- one coalesced 64-lane load covers ids+mask for this wave's 4 paths ----
    const int base = (s * P_PATHS + wave * 4) * K_EP;   // 64 endpoint slots
    const int idv  = eids[base + lane];
    int mk;
    if (floatMask)     mk = (((const float*)emask)[base + lane] != 0.0f);
    else if (byteMask) mk = ((const unsigned char*)emask)[base + lane];
    else               mk = ((const int*)emask)[base + lane];
    const unsigned long long bits_all = __ballot(mk != 0);

    const int half = lane >> 5;      // which 32-lane half (owns even/odd rows of the batch)
    const int col  = lane & 31;      // float4 column within a row

    // ---- gather: per path, ALL rows issued as one batch of 8 float4 loads (2 rows/instr) ----
    #pragma unroll
    for (int i = 0; i < 4; ++i) {
        const int p = wave * 4 + i;
        const unsigned int bits = (unsigned int)((bits_all >> (16 * i)) & 0xFFFFu);
        const int cnt = __popc(bits);
        float ax = 0.f, ay = 0.f, az = 0.f, aw = 0.f;
        if (bits) {
            int pos[16];
            unsigned int b = bits;
            const int k0 = __builtin_ctz(bits);
            #pragma unroll
            for (int u = 0; u < 16; ++u) { pos[u] = b ? __builtin_ctz(b) : k0; b &= b - 1; }
            float4 v[8];
            int vld[8];
            #pragma unroll
            for (int u = 0; u < 8; ++u) {
                const int slot = 2 * u + half;
                const int ps   = half ? pos[2 * u + 1] : pos[2 * u];
                const int id   = __shfl(idv, 16 * i + ps);   // safe fallback row when slot>=cnt
                v[u]   = ((const float4*)(ent + (size_t)id * D_DIM))[col];
                vld[u] = (slot < cnt);
            }
            #pragma unroll
            for (int u = 0; u < 8; ++u) {
                if (vld[u]) { ax += v[u].x; ay += v[u].y; az += v[u].z; aw += v[u].w; }
            }
        }
        // merge the two half-wave partial sums (both halves end with the full sum)
        ax += __shfl_xor(ax, 32); ay += __shfl_xor(ay, 32);
        az += __shfl_xor(az, 32); aw += __shfl_xor(aw, 32);
        const float inv = 1.0f / (float)(cnt > 1 ? cnt : 1);
        ax *= inv; ay *= inv; az *= inv; aw *= inv;
        if (half == 0) {
            *(float4*)&aggf[p][col * 4] = make_float4(ax, ay, az, aw);
            union { __bf16 h[4]; uint2 u; } pk;
            pk.h[0] = (__bf16)ax; pk.h[1] = (__bf16)ay;
            pk.h[2] = (__bf16)az; pk.h[3] = (__bf16)aw;
            *(uint2*)&aggbf[p][col * 4] = pk.u;
        }
        if (lane == 0) cnts[p] = cnt;
    }
    __syncthreads();

    if (wave != 0) return;

    // ---- MLP for all 16 paths at once via MFMA (wave 0 only) ----
    // A[m][k]: m = lane&15, k = (lane>>4)*8 + j ; B[k][n]: n = lane&15, same k
    // D[m][n]: n = lane&15, m = (lane>>4)*4 + reg
    const int m    = lane & 15;
    const int quad = lane >> 4;

    bf16x8_t afr[4];
    #pragma unroll
    for (int st = 0; st < 4; ++st)
        afr[st] = *(const bf16x8_t*)&aggbf[m][st * 32 + quad * 8];

    float xp[4] = {0.f, 0.f, 0.f, 0.f};
    #pragma unroll
    for (int t = 0; t < 4; ++t) {              // j-tile (16 cols each)
        const int n = t * 16 + m;
        const float b1v = b1s[n];
        f32x4_t acc = {b1v, b1v, b1v, b1v};    // fold b1 into C-init
        #pragma unroll
        for (int st = 0; st < 4; ++st) {       // K-steps of 32
            // w1t rows are 260B (4B-aligned) -> assemble fragment from 4x b32 reads
            union { unsigned int u[4]; bf16x8_t v; } bfr;
            const __bf16* bp = &w1t[n][st * 32 + quad * 8];
            #pragma unroll
            for (int r = 0; r < 4; ++r) bfr.u[r] = *(const unsigned int*)(bp + 2 * r);
            acc = __builtin_amdgcn_mfma_f32_16x16x32_bf16(afr[st], bfr.v, acc, 0, 0, 0);
        }
        const float w2v = w2s[n];
        #pragma unroll
        for (int r = 0; r < 4; ++r) {
            float h = acc[r] > 0.f ? acc[r] : 0.f;   // relu
            xp[r] += h * w2v;
        }
    }
    // reduce over the 16 lanes of each quad (sum over n)
    #pragma unroll
    for (int off = 1; off < 16; off <<= 1) {
        #pragma unroll
        for (int r = 0; r < 4; ++r) xp[r] += __shfl_xor(xp[r], off);
    }

    int myc[4]; int localv = 0;
    #pragma unroll
    for (int r = 0; r < 4; ++r) { myc[r] = cnts[quad * 4 + r]; localv += (myc[r] > 0); }
    int nv = localv + __shfl_xor(localv, 16);
    nv += __shfl_xor(nv, 32);
    const float invnv = 1.0f / (float)(nv > 1 ? nv : 1);
    const float b2v = b2[0];

    float wv[4];
    #pragma unroll
    for (int r = 0; r < 4; ++r) {
        float x = xp[r] + b2v;
        float w = 1.0f / (1.0f + __expf(-x));
        wv[r] = (myc[r] > 0) ? w * invnv : 0.f;   // invalid paths contribute 0
    }

    // broadcast all 16 path weights, accumulate node feature (fp32 agg)
    float fx = 0.f, fy = 0.f;
    #pragma unroll
    for (int p = 0; p < P_PATHS; ++p) {
        float wp = __shfl(wv[p & 3], (p >> 2) << 4);
        float2 a = *(const float2*)&aggf[p][2 * lane];
        fx += wp * a.x; fy += wp * a.y;
    }
    const int row = sids[s];
    *(float2*)&out[(size_t)row * D_DIM + 2 * lane] = make_float2(fx, fy);
}

extern "C" void kernel_launch(void* const* d_in, const int* in_sizes, int n_in,
                              void* d_out, int out_size, void* d_ws, size_t ws_size,
                              hipStream_t stream)
{
    const float* ent  = (const float*)d_in[0];
    const float* W1   = (const float*)d_in[1];
    const float* b1   = (const float*)d_in[2];
    const float* W2   = (const float*)d_in[3];
    const float* b2   = (const float*)d_in[4];
    const int*   sids = (const int*)d_in[5];
    const int*   eids = (const int*)d_in[6];
    const void*  emsk = (const void*)d_in[7];
    float* out = (float*)d_out;

    // zero the whole [N,D] output (rows not hit by the scatter must be 0; d_out is poisoned)
    hipMemsetAsync(d_out, 0, (size_t)out_size * sizeof(float), stream);
    PathGuidedAggregator_kernel<<<S_NODES, 256, 0, stream>>>(ent, W1, b1, W2, b2, sids, eids, emsk, out);
}

// Round 3
// 212.228 us; speedup vs baseline: 1.2713x; 1.2713x over previous
//
#include <hip/hip_runtime.h>
#include <hip/hip_bf16.h>

#define S_NODES 8192
#define P_PATHS 16
#define K_EP    16
#define D_DIM   128
#define H_DIM   64

typedef __bf16 bf16x8_t __attribute__((ext_vector_type(8)));
typedef float  f32x4_t  __attribute__((ext_vector_type(4)));

// LDS strides (elements per row), every hot access <=2-way bank aliased (free):
#define AGGF_STRIDE  132   // floats; dense float4 writes -> conflict-free
#define AGGBF_STRIDE 136   // bf16; 272B rows, 16B-aligned for b128 A-frag reads
#define W1T_STRIDE   130   // bf16; staging lane-stride 65 words == 1 mod 32 -> conflict-free

__global__ __launch_bounds__(256)
void PathGuidedAggregator_kernel(const float* __restrict__ ent,
                                 const float* __restrict__ W1,
                                 const float* __restrict__ b1,
                                 const float* __restrict__ W2,
                                 const float* __restrict__ b2,
                                 const int*   __restrict__ sids,
                                 const int*   __restrict__ eids,
                                 const void*  __restrict__ emask,
                                 float*       __restrict__ out)
{
    __shared__ float  aggf [P_PATHS][AGGF_STRIDE];   // fp32 agg (epilogue w*agg)
    __shared__ __bf16 aggbf[P_PATHS][AGGBF_STRIDE];  // bf16 agg (MFMA A operand)
    __shared__ __bf16 w1t  [H_DIM][W1T_STRIDE];      // W1^T [j][d] (MFMA B operand)
    __shared__ float  b1s[H_DIM];
    __shared__ float  w2s[H_DIM];
    __shared__ int    cnts[P_PATHS];
    __shared__ int    comp[4][4][K_EP];              // per-wave compacted endpoint ids

    const int s    = blockIdx.x;
    const int tid  = threadIdx.x;
    const int wave = tid >> 6;
    const int lane = tid & 63;

    // ---- stage W1 (transposed -> bf16) into LDS ----
    #pragma unroll
    for (int it = 0; it < 32; ++it) {
        int idx = tid + it * 256;            // coalesced read of W1[d][j]
        int d = idx >> 6, j = idx & 63;
        w1t[j][d] = (__bf16)W1[idx];
    }
    if (tid < H_DIM) { b1s[tid] = b1[tid]; w2s[tid] = W2[tid]; }

    // ---- runtime detection of bool-mask storage: int32 / uint8 / float32 ----
    const unsigned int* mw = (const unsigned int*)emask;
    unsigned int probe = mw[lane];
    const bool floatMask = (__ballot(probe == 0x3F800000u) != 0ULL);
    const bool byteMask  = !floatMask && (__ballot(probe > 1u) != 0ULL);

    // ---- one coalesced 64-lane load covers ids+mask for this wave's 4 paths ----
    const int base = (s * P_PATHS + wave * 4) * K_EP;   // 64 endpoint slots
    const int idv  = eids[base + lane];
    int mk;
    if (floatMask)     mk = (((const float*)emask)[base + lane] != 0.0f);
    else if (byteMask) mk = ((const unsigned char*)emask)[base + lane];
    else               mk = ((const int*)emask)[base + lane];
    const unsigned long long bits_all = __ballot(mk != 0);

    const int k16  = lane & 15;      // slot within path
    const int pgrp = lane >> 4;      // which of the wave's 4 paths this lane's id belongs to
    const unsigned int bits_p = (unsigned int)((bits_all >> (16 * pgrp)) & 0xFFFFu);

    // compact valid ids into LDS (slots >= cnt stay 0 -> safe row, masked out later)
    comp[wave][pgrp][k16] = 0;
    if (mk) comp[wave][pgrp][__popc(bits_p & ((1u << k16) - 1u))] = idv;
    if (lane < 4) cnts[wave * 4 + lane] = __popc((unsigned int)((bits_all >> (16 * lane)) & 0xFFFFu));

    const int c0 = __popc((unsigned int)( bits_all        & 0xFFFFu));
    const int c1 = __popc((unsigned int)((bits_all >> 16) & 0xFFFFu));
    const int c2 = __popc((unsigned int)((bits_all >> 32) & 0xFFFFu));
    const int c3 = __popc((unsigned int)((bits_all >> 48) & 0xFFFFu));

    const int half = lane >> 5;      // half-wave owns even/odd slots
    const int col  = lane & 31;      // float4 column within a row
    const float4* __restrict__ entc = (const float4*)ent + col;  // + id*32 per row

    // ---- gather: 4 paths x 8 slots of guarded float4 loads, 4 independent acc chains ----
    float4 acc0 = {0.f,0.f,0.f,0.f}, acc1 = acc0, acc2 = acc0, acc3 = acc0;
    #pragma unroll
    for (int u = 0; u < 8; ++u) {
        const int slot = 2 * u + half;
        const int id0 = comp[wave][0][slot];
        const int id1 = comp[wave][1][slot];
        const int id2 = comp[wave][2][slot];
        const int id3 = comp[wave][3][slot];
        if (slot < c0) { float4 v = entc[(size_t)id0 << 5]; acc0.x += v.x; acc0.y += v.y; acc0.z += v.z; acc0.w += v.w; }
        if (slot < c1) { float4 v = entc[(size_t)id1 << 5]; acc1.x += v.x; acc1.y += v.y; acc1.z += v.z; acc1.w += v.w; }
        if (slot < c2) { float4 v = entc[(size_t)id2 << 5]; acc2.x += v.x; acc2.y += v.y; acc2.z += v.z; acc2.w += v.w; }
        if (slot < c3) { float4 v = entc[(size_t)id3 << 5]; acc3.x += v.x; acc3.y += v.y; acc3.z += v.z; acc3.w += v.w; }
    }

    // merge half-wave partials, normalize, store to LDS
    #pragma unroll
    for (int i = 0; i < 4; ++i) {
        float4 a = (i == 0) ? acc0 : (i == 1) ? acc1 : (i == 2) ? acc2 : acc3;
        const int cnt = (i == 0) ? c0 : (i == 1) ? c1 : (i == 2) ? c2 : c3;
        a.x += __shfl_xor(a.x, 32); a.y += __shfl_xor(a.y, 32);
        a.z += __shfl_xor(a.z, 32); a.w += __shfl_xor(a.w, 32);
        const float inv = 1.0f / (float)(cnt > 1 ? cnt : 1);
        a.x *= inv; a.y *= inv; a.z *= inv; a.w *= inv;
        if (half == 0) {
            const int p = wave * 4 + i;
            *(float4*)&aggf[p][col * 4] = a;
            union { __bf16 h[4]; uint2 u2; } pk;
            pk.h[0] = (__bf16)a.x; pk.h[1] = (__bf16)a.y;
            pk.h[2] = (__bf16)a.z; pk.h[3] = (__bf16)a.w;
            *(uint2*)&aggbf[p][col * 4] = pk.u2;
        }
    }
    __syncthreads();

    if (wave != 0) return;

    // ---- MLP for all 16 paths at once via MFMA (wave 0 only) ----
    // A[m][k]: m=lane&15, k=(lane>>4)*8+j ; B[k][n]: n=lane&15, same k
    // D[m][n]: n=lane&15, m=(lane>>4)*4+reg
    const int m    = lane & 15;
    const int quad = lane >> 4;

    bf16x8_t afr[4];
    #pragma unroll
    for (int st = 0; st < 4; ++st)
        afr[st] = *(const bf16x8_t*)&aggbf[m][st * 32 + quad * 8];

    float xp[4] = {0.f, 0.f, 0.f, 0.f};
    #pragma unroll
    for (int t = 0; t < 4; ++t) {              // j-tile (16 cols each)
        const int n = t * 16 + m;
        const float b1v = b1s[n];
        f32x4_t acc = {b1v, b1v, b1v, b1v};    // fold b1 into C-init
        #pragma unroll
        for (int st = 0; st < 4; ++st) {       // K-steps of 32
            union { unsigned int u[4]; bf16x8_t v; } bfr;   // rows are 4B-aligned
            const __bf16* bp = &w1t[n][st * 32 + quad * 8];
            #pragma unroll
            for (int r = 0; r < 4; ++r) bfr.u[r] = *(const unsigned int*)(bp + 2 * r);
            acc = __builtin_amdgcn_mfma_f32_16x16x32_bf16(afr[st], bfr.v, acc, 0, 0, 0);
        }
        const float w2v = w2s[n];
        #pragma unroll
        for (int r = 0; r < 4; ++r) {
            float h = acc[r] > 0.f ? acc[r] : 0.f;   // relu
            xp[r] += h * w2v;
        }
    }
    // reduce over the 16 lanes of each quad (sum over n)
    #pragma unroll
    for (int off = 1; off < 16; off <<= 1) {
        #pragma unroll
        for (int r = 0; r < 4; ++r) xp[r] += __shfl_xor(xp[r], off);
    }

    int myc[4]; int localv = 0;
    #pragma unroll
    for (int r = 0; r < 4; ++r) { myc[r] = cnts[quad * 4 + r]; localv += (myc[r] > 0); }
    int nv = localv + __shfl_xor(localv, 16);
    nv += __shfl_xor(nv, 32);
    const float invnv = 1.0f / (float)(nv > 1 ? nv : 1);
    const float b2v = b2[0];

    float wv[4];
    #pragma unroll
    for (int r = 0; r < 4; ++r) {
        float x = xp[r] + b2v;
        float w = 1.0f / (1.0f + __expf(-x));
        wv[r] = (myc[r] > 0) ? w * invnv : 0.f;   // invalid paths contribute 0
    }

    // broadcast all 16 path weights, accumulate node feature (fp32 agg)
    float fx = 0.f, fy = 0.f;
    #pragma unroll
    for (int p = 0; p < P_PATHS; ++p) {
        float wp = __shfl(wv[p & 3], (p >> 2) << 4);
        float2 a = *(const float2*)&aggf[p][2 * lane];
        fx += wp * a.x; fy += wp * a.y;
    }
    const int row = sids[s];
    *(float2*)&out[(size_t)row * D_DIM + 2 * lane] = make_float2(fx, fy);
}

extern "C" void kernel_launch(void* const* d_in, const int* in_sizes, int n_in,
                              void* d_out, int out_size, void* d_ws, size_t ws_size,
                              hipStream_t stream)
{
    const float* ent  = (const float*)d_in[0];
    const float* W1   = (const float*)d_in[1];
    const float* b1   = (const float*)d_in[2];
    const float* W2   = (const float*)d_in[3];
    const float* b2   = (const float*)d_in[4];
    const int*   sids = (const int*)d_in[5];
    const int*   eids = (const int*)d_in[6];
    const void*  emsk = (const void*)d_in[7];
    float* out = (float*)d_out;

    // zero the whole [N,D] output (rows not hit by the scatter must be 0; d_out is poisoned)
    hipMemsetAsync(d_out, 0, (size_t)out_size * sizeof(float), stream);
    PathGuidedAggregator_kernel<<<S_NODES, 256, 0, stream>>>(ent, W1, b1, W2, b2, sids, eids, emsk, out);
}

// Round 4
// 188.676 us; speedup vs baseline: 1.4299x; 1.1248x over previous
//
#include <hip/hip_runtime.h>
#include <hip/hip_bf16.h>

#define S_NODES 8192
#define P_PATHS 16
#define K_EP    16
#define D_DIM   128
#define H_DIM   64

typedef __bf16 bf16x8_t __attribute__((ext_vector_type(8)));
typedef float  f32x4_t  __attribute__((ext_vector_type(4)));

// LDS strides (elements per row), every hot access <=2-way bank aliased (free):
#define AGGF_STRIDE  132   // floats; dense float4 writes -> conflict-free
#define AGGBF_STRIDE 136   // bf16; 272B rows, 16B-aligned for b128 A-frag reads

// ---- prep: W1 [D][H] fp32 -> W1^T [H][D] bf16 in workspace (run once per launch) ----
__global__ __launch_bounds__(256)
void prep_w1_kernel(const float* __restrict__ W1, __bf16* __restrict__ w1t)
{
    const int idx = blockIdx.x * 256 + threadIdx.x;   // 32 blocks x 256 = 8192
    const int n = idx >> 7, d = idx & 127;
    w1t[idx] = (__bf16)W1[d * H_DIM + n];
}

__global__ __launch_bounds__(256, 8)   // cap VGPR<=64 -> 8 waves/SIMD (100% occupancy)
void PathGuidedAggregator_kernel(const float* __restrict__ ent,
                                 const float* __restrict__ b1,
                                 const float* __restrict__ W2,
                                 const float* __restrict__ b2,
                                 const int*   __restrict__ sids,
                                 const int*   __restrict__ eids,
                                 const void*  __restrict__ emask,
                                 const __bf16* __restrict__ w1t,   // [H][D] bf16 (prep output)
                                 float*       __restrict__ out)
{
    __shared__ float  aggf [P_PATHS][AGGF_STRIDE];   // fp32 agg (epilogue w*agg)
    __shared__ __bf16 aggbf[P_PATHS][AGGBF_STRIDE];  // bf16 agg (MFMA A operand)
    __shared__ int    cnts[P_PATHS];
    __shared__ int    comp[4][4][K_EP];              // per-wave compacted endpoint ids

    const int s    = blockIdx.x;
    const int tid  = threadIdx.x;
    const int wave = tid >> 6;
    const int lane = tid & 63;

    // ---- runtime detection of bool-mask storage: int32 / uint8 / float32 ----
    const unsigned int* mw = (const unsigned int*)emask;
    unsigned int probe = mw[lane];
    const bool floatMask = (__ballot(probe == 0x3F800000u) != 0ULL);
    const bool byteMask  = !floatMask && (__ballot(probe > 1u) != 0ULL);

    // ---- one coalesced 64-lane load covers ids+mask for this wave's 4 paths ----
    const int base = (s * P_PATHS + wave * 4) * K_EP;   // 64 endpoint slots
    const int idv  = eids[base + lane];
    int mk;
    if (floatMask)     mk = (((const float*)emask)[base + lane] != 0.0f);
    else if (byteMask) mk = ((const unsigned char*)emask)[base + lane];
    else               mk = ((const int*)emask)[base + lane];
    const unsigned long long bits_all = __ballot(mk != 0);

    const int k16  = lane & 15;      // slot within path
    const int pgrp = lane >> 4;      // which of the wave's 4 paths this lane's id belongs to
    const unsigned int bits_p = (unsigned int)((bits_all >> (16 * pgrp)) & 0xFFFFu);

    // compact valid ids into LDS (slots >= cnt stay 0 -> safe row, masked out later)
    comp[wave][pgrp][k16] = 0;
    if (mk) comp[wave][pgrp][__popc(bits_p & ((1u << k16) - 1u))] = idv;
    if (lane < 4) cnts[wave * 4 + lane] = __popc((unsigned int)((bits_all >> (16 * lane)) & 0xFFFFu));

    const int c0 = __popc((unsigned int)( bits_all        & 0xFFFFu));
    const int c1 = __popc((unsigned int)((bits_all >> 16) & 0xFFFFu));
    const int c2 = __popc((unsigned int)((bits_all >> 32) & 0xFFFFu));
    const int c3 = __popc((unsigned int)((bits_all >> 48) & 0xFFFFu));

    const int half = lane >> 5;      // half-wave owns even/odd slots
    const int col  = lane & 31;      // float4 column within a row
    const float4* __restrict__ entc = (const float4*)ent + col;  // + id*32 per row

    // ---- gather: 4 paths x 8 slots of guarded float4 loads, 4 independent acc chains ----
    float4 acc0 = {0.f,0.f,0.f,0.f}, acc1 = acc0, acc2 = acc0, acc3 = acc0;
    #pragma unroll
    for (int u = 0; u < 8; ++u) {
        const int slot = 2 * u + half;
        const int id0 = comp[wave][0][slot];
        const int id1 = comp[wave][1][slot];
        const int id2 = comp[wave][2][slot];
        const int id3 = comp[wave][3][slot];
        if (slot < c0) { float4 v = entc[(size_t)id0 << 5]; acc0.x += v.x; acc0.y += v.y; acc0.z += v.z; acc0.w += v.w; }
        if (slot < c1) { float4 v = entc[(size_t)id1 << 5]; acc1.x += v.x; acc1.y += v.y; acc1.z += v.z; acc1.w += v.w; }
        if (slot < c2) { float4 v = entc[(size_t)id2 << 5]; acc2.x += v.x; acc2.y += v.y; acc2.z += v.z; acc2.w += v.w; }
        if (slot < c3) { float4 v = entc[(size_t)id3 << 5]; acc3.x += v.x; acc3.y += v.y; acc3.z += v.z; acc3.w += v.w; }
    }

    // merge half-wave partials, normalize, store to LDS
    #pragma unroll
    for (int i = 0; i < 4; ++i) {
        float4 a = (i == 0) ? acc0 : (i == 1) ? acc1 : (i == 2) ? acc2 : acc3;
        const int cnt = (i == 0) ? c0 : (i == 1) ? c1 : (i == 2) ? c2 : c3;
        a.x += __shfl_xor(a.x, 32); a.y += __shfl_xor(a.y, 32);
        a.z += __shfl_xor(a.z, 32); a.w += __shfl_xor(a.w, 32);
        const float inv = 1.0f / (float)(cnt > 1 ? cnt : 1);
        a.x *= inv; a.y *= inv; a.z *= inv; a.w *= inv;
        if (half == 0) {
            const int p = wave * 4 + i;
            *(float4*)&aggf[p][col * 4] = a;
            union { __bf16 h[4]; uint2 u2; } pk;
            pk.h[0] = (__bf16)a.x; pk.h[1] = (__bf16)a.y;
            pk.h[2] = (__bf16)a.z; pk.h[3] = (__bf16)a.w;
            *(uint2*)&aggbf[p][col * 4] = pk.u2;
        }
    }
    __syncthreads();

    if (wave != 0) return;

    // ---- MLP for all 16 paths at once via MFMA (wave 0 only) ----
    // A[m][k]: m=lane&15, k=(lane>>4)*8+j ; B[k][n]: n=lane&15, same k
    // D[m][n]: n=lane&15, m=(lane>>4)*4+reg
    const int m    = lane & 15;
    const int quad = lane >> 4;

    bf16x8_t afr[4];
    #pragma unroll
    for (int st = 0; st < 4; ++st)
        afr[st] = *(const bf16x8_t*)&aggbf[m][st * 32 + quad * 8];

    float xp[4] = {0.f, 0.f, 0.f, 0.f};
    #pragma unroll
    for (int t = 0; t < 4; ++t) {              // j-tile (16 cols each)
        const int n = t * 16 + m;
        const float b1v = b1[n];
        f32x4_t acc = {b1v, b1v, b1v, b1v};    // fold b1 into C-init
        const __bf16* bp = w1t + n * D_DIM + quad * 8;   // B-fragments straight from global (L2-hot)
        #pragma unroll
        for (int st = 0; st < 4; ++st) {       // K-steps of 32
            bf16x8_t bfr = *(const bf16x8_t*)(bp + st * 32);
            acc = __builtin_amdgcn_mfma_f32_16x16x32_bf16(afr[st], bfr, acc, 0, 0, 0);
        }
        const float w2v = W2[n];
        #pragma unroll
        for (int r = 0; r < 4; ++r) {
            float h = acc[r] > 0.f ? acc[r] : 0.f;   // relu
            xp[r] += h * w2v;
        }
    }
    // reduce over the 16 lanes of each quad (sum over n)
    #pragma unroll
    for (int off = 1; off < 16; off <<= 1) {
        #pragma unroll
        for (int r = 0; r < 4; ++r) xp[r] += __shfl_xor(xp[r], off);
    }

    int myc[4]; int localv = 0;
    #pragma unroll
    for (int r = 0; r < 4; ++r) { myc[r] = cnts[quad * 4 + r]; localv += (myc[r] > 0); }
    int nv = localv + __shfl_xor(localv, 16);
    nv += __shfl_xor(nv, 32);
    const float invnv = 1.0f / (float)(nv > 1 ? nv : 1);
    const float b2v = b2[0];

    float wv[4];
    #pragma unroll
    for (int r = 0; r < 4; ++r) {
        float x = xp[r] + b2v;
        float w = 1.0f / (1.0f + __expf(-x));
        wv[r] = (myc[r] > 0) ? w * invnv : 0.f;   // invalid paths contribute 0
    }

    // broadcast all 16 path weights, accumulate node feature (fp32 agg)
    float fx = 0.f, fy = 0.f;
    #pragma unroll
    for (int p = 0; p < P_PATHS; ++p) {
        float wp = __shfl(wv[p & 3], (p >> 2) << 4);
        float2 a = *(const float2*)&aggf[p][2 * lane];
        fx += wp * a.x; fy += wp * a.y;
    }
    const int row = sids[s];
    *(float2*)&out[(size_t)row * D_DIM + 2 * lane] = make_float2(fx, fy);
}

extern "C" void kernel_launch(void* const* d_in, const int* in_sizes, int n_in,
                              void* d_out, int out_size, void* d_ws, size_t ws_size,
                              hipStream_t stream)
{
    const float* ent  = (const float*)d_in[0];
    const float* W1   = (const float*)d_in[1];
    const float* b1   = (const float*)d_in[2];
    const float* W2   = (const float*)d_in[3];
    const float* b2   = (const float*)d_in[4];
    const int*   sids = (const int*)d_in[5];
    const int*   eids = (const int*)d_in[6];
    const void*  emsk = (const void*)d_in[7];
    float* out = (float*)d_out;
    __bf16* w1t_ws = (__bf16*)d_ws;          // 8192 bf16 = 16 KB

    // zero the whole [N,D] output (rows not hit by the scatter must be 0; d_out is poisoned)
    hipMemsetAsync(d_out, 0, (size_t)out_size * sizeof(float), stream);
    prep_w1_kernel<<<32, 256, 0, stream>>>(W1, w1t_ws);
    PathGuidedAggregator_kernel<<<S_NODES, 256, 0, stream>>>(ent, b1, W2, b2, sids, eids, emsk,
                                                             (const __bf16*)w1t_ws, out);
}